// Round 14
// baseline (209.339 us; speedup 1.0000x reference)
//
#include <hip/hip_runtime.h>
#include <hip/hip_fp16.h>
#include <math.h>

// Problem constants
#define NPROJ 4112          // P = 2*H*K + H*V + 2*H + UNITS
#define HOFF  0                                  // h_t  : 512*1024
#define COFF  524288                             // C_t  : 512*8*128*128
#define NOFF  67633152                           // n_t  : 512*1024
#define SLICE 2105344                            // 512*4112 (one split-K partial)

using f16x8 = __attribute__((ext_vector_type(8))) _Float16;
using f32x4 = __attribute__((ext_vector_type(4))) float;

typedef __attribute__((address_space(1))) const ushort gu16;
typedef __attribute__((address_space(3))) ushort lu16;

#define ASCALE 64.0f        // pre-scale: keeps fp16 lo-parts out of denormal range
#define PSCALE (1.0 / 4096.0)   // exact 2^-12 undo in fp64

__device__ __forceinline__ void fp16_split(float x, ushort& h, ushort& l)
{
    const __half h1 = __float2half(x);
    h = __half_as_ushort(h1);
    l = __half_as_ushort(__float2half(x - __half2float(h1)));
}

// ---------------------------------------------------------------------------
// S1: A = [X0 | X1] * 64  ->  fp16 hi/lo, row-major [512][2048] (k-contig).
// ---------------------------------------------------------------------------
__global__ __launch_bounds__(256)
void split_a2(const float* __restrict__ X0, const float* __restrict__ X1,
              ushort* __restrict__ Ah, ushort* __restrict__ Al)
{
    const int idx8 = (blockIdx.x * 256 + threadIdx.x) << 3;   // 0..1048568
    const int row = idx8 >> 11, k = idx8 & 2047;
    const float* src = (k < 1024) ? (X0 + (size_t)row * 1024 + k)
                                  : (X1 + (size_t)row * 1024 + (k - 1024));
    const float4 v0 = *(const float4*)src;
    const float4 v1 = *(const float4*)(src + 4);
    const float vv[8] = {v0.x, v0.y, v0.z, v0.w, v1.x, v1.y, v1.z, v1.w};
    ushort hh[8], ll[8];
#pragma unroll
    for (int i = 0; i < 8; ++i) fp16_split(vv[i] * ASCALE, hh[i], ll[i]);
    uint4 uh, ul;
    uh.x = hh[0] | ((unsigned)hh[1] << 16); uh.y = hh[2] | ((unsigned)hh[3] << 16);
    uh.z = hh[4] | ((unsigned)hh[5] << 16); uh.w = hh[6] | ((unsigned)hh[7] << 16);
    ul.x = ll[0] | ((unsigned)ll[1] << 16); ul.y = ll[2] | ((unsigned)ll[3] << 16);
    ul.z = ll[4] | ((unsigned)ll[5] << 16); ul.w = ll[6] | ((unsigned)ll[7] << 16);
    *(uint4*)(Ah + idx8) = uh;
    *(uint4*)(Al + idx8) = ul;
}

// ---------------------------------------------------------------------------
// S2: Wt = transpose([W0;W1]) * 64 -> fp16 hi/lo, [4096][2048] (n-major,
// k-contig). Cols 4096..4111 handled by proj_tail4. Grid (32 k, 64 n).
// ---------------------------------------------------------------------------
__global__ __launch_bounds__(256)
void split_w2(const float* __restrict__ W0, const float* __restrict__ W1,
              ushort* __restrict__ Wh, ushort* __restrict__ Wl)
{
    __shared__ __align__(16) ushort Th[64][72];
    __shared__ __align__(16) ushort Tl[64][72];
    const int t = threadIdx.x;
    const int kcat0 = blockIdx.x * 64;       // 0..1984
    const int n0    = blockIdx.y * 64;       // 0..4032
    const float* __restrict__ W = (kcat0 < 1024) ? W0 : W1;
    const int kbase = kcat0 & 1023;
    const int kr = t >> 4;                   // 0..15
    const int nc = (t & 15) << 2;            // 0..60
#pragma unroll
    for (int ii = 0; ii < 4; ++ii) {
        const int kl = kr + ii * 16;
        const float4 w = *(const float4*)(W + (size_t)(kbase + kl) * NPROJ + n0 + nc);
        const float x[4] = {w.x, w.y, w.z, w.w};
#pragma unroll
        for (int c = 0; c < 4; ++c) {
            ushort hh, ll;
            fp16_split(x[c] * ASCALE, hh, ll);
            Th[nc + c][kl] = hh;
            Tl[nc + c][kl] = ll;
        }
    }
    __syncthreads();
#pragma unroll
    for (int p = 0; p < 2; ++p) {
        const int c  = t + (p << 8);         // 0..511
        const int nn = c >> 3;
        const int kq = (c & 7) << 3;
        *(uint4*)(Wh + (size_t)(n0 + nn) * 2048 + kcat0 + kq) = *(uint4*)&Th[nn][kq];
        *(uint4*)(Wl + (size_t)(n0 + nn) * 2048 + kcat0 + kq) = *(uint4*)&Tl[nn][kq];
    }
}

// ---------------------------------------------------------------------------
// G: pbuf[z] = Xz * Wz (scaled) via fp16x2 MFMA, 3 terms (hh, hl, lh).
// Tile 64x64, BK=64 phases, DOUBLE-BUFFERED 64KB LDS, ONE barrier per phase:
// glds for phase kt+1 issued before phase kt's 16 ds_read + 24 MFMA, so the
// ~250cyc L2 latency hides under compute (T3 minimum recipe, R13's mistake
// was BK=32 phases: too little compute to hide under + 2x barriers).
// Grid (64, 8, 2) = 1024 blocks = EXACTLY 2 blocks/CU, zero tail rounds.
// XOR-8 swizzle (R12-proven): pre-swizzled SOURCE, linear dest, swizzled read.
// ---------------------------------------------------------------------------
__global__ __launch_bounds__(256)
void proj_mfma4(const ushort* __restrict__ Ah, const ushort* __restrict__ Al,
                const ushort* __restrict__ Wh, const ushort* __restrict__ Wl,
                float* __restrict__ pbuf)
{
    __shared__ __align__(16) ushort As[2][2][4096];   // [buf][lvl][r*64 + slot*8]
    __shared__ __align__(16) ushort Bs[2][2][4096];

    const int t    = threadIdx.x;
    const int col0 = blockIdx.x * 64;        // 0..4032 (cols < 4096 always)
    const int row0 = blockIdx.y * 64;
    const int z    = blockIdx.z;             // kcat base = z*1024
    const int lane = t & 63, wid = t >> 6;
    const int wr = wid >> 1, wc = wid & 1;
    const int lr = lane & 15, lq = lane >> 4;

    // staging: thread covers 16B chunks c0 = t (rows 0..31), c1 = t+256 (rows 32..63)
    const int r0s = t >> 3, ch0 = t & 7;
    const int r1s = r0s + 32;
    const int so0 = (ch0 ^ (r0s & 7)) << 3;  // pre-swizzled src offset (halves)
    const int so1 = (ch0 ^ (r1s & 7)) << 3;
    const size_t kb = (size_t)z << 10;
    const size_t arow0 = (size_t)(row0 + r0s) * 2048 + kb;
    const size_t arow1 = (size_t)(row0 + r1s) * 2048 + kb;
    const size_t brow0 = (size_t)(col0 + r0s) * 2048 + kb;
    const size_t brow1 = (size_t)(col0 + r1s) * 2048 + kb;
    const int d0 = t << 3, d1 = d0 + 2048;   // linear LDS dest (halves)

#define STG4(BUF, KT)                                                                             \
    {                                                                                             \
        const int ko = (KT) << 6;                                                                 \
        __builtin_amdgcn_global_load_lds((gu16*)(Ah + arow0 + ko + so0), (lu16*)&As[BUF][0][d0], 16, 0, 0); \
        __builtin_amdgcn_global_load_lds((gu16*)(Ah + arow1 + ko + so1), (lu16*)&As[BUF][0][d1], 16, 0, 0); \
        __builtin_amdgcn_global_load_lds((gu16*)(Al + arow0 + ko + so0), (lu16*)&As[BUF][1][d0], 16, 0, 0); \
        __builtin_amdgcn_global_load_lds((gu16*)(Al + arow1 + ko + so1), (lu16*)&As[BUF][1][d1], 16, 0, 0); \
        __builtin_amdgcn_global_load_lds((gu16*)(Wh + brow0 + ko + so0), (lu16*)&Bs[BUF][0][d0], 16, 0, 0); \
        __builtin_amdgcn_global_load_lds((gu16*)(Wh + brow1 + ko + so1), (lu16*)&Bs[BUF][0][d1], 16, 0, 0); \
        __builtin_amdgcn_global_load_lds((gu16*)(Wl + brow0 + ko + so0), (lu16*)&Bs[BUF][1][d0], 16, 0, 0); \
        __builtin_amdgcn_global_load_lds((gu16*)(Wl + brow1 + ko + so1), (lu16*)&Bs[BUF][1][d1], 16, 0, 0); \
    }

    // fragment read offsets (halves, within one [lvl] plane)
    int aoff[2][2], boff[2][2];
#pragma unroll
    for (int mi = 0; mi < 2; ++mi)
#pragma unroll
        for (int kh = 0; kh < 2; ++kh) {
            const int ra = (wr << 5) + (mi << 4) + lr;
            aoff[mi][kh] = (ra << 6) + ((((kh << 2) + lq) ^ (ra & 7)) << 3);
            const int rb = (wc << 5) + (mi << 4) + lr;
            boff[mi][kh] = (rb << 6) + ((((kh << 2) + lq) ^ (rb & 7)) << 3);
        }

    f32x4 acc[2][2] = {};

    STG4(0, 0)
    __syncthreads();   // drains prologue staging

    for (int kt = 0; kt < 16; ++kt) {
        const int cur = kt & 1;
        if (kt + 1 < 16) STG4(cur ^ 1, kt + 1)   // in flight under this phase's compute

#pragma unroll
        for (int kh = 0; kh < 2; ++kh) {
            f16x8 ah[2], al[2], bh[2], bl[2];
#pragma unroll
            for (int mi = 0; mi < 2; ++mi) {
                ah[mi] = *(const f16x8*)&As[cur][0][aoff[mi][kh]];
                al[mi] = *(const f16x8*)&As[cur][1][aoff[mi][kh]];
                bh[mi] = *(const f16x8*)&Bs[cur][0][boff[mi][kh]];
                bl[mi] = *(const f16x8*)&Bs[cur][1][boff[mi][kh]];
            }
#pragma unroll
            for (int mi = 0; mi < 2; ++mi)
#pragma unroll
                for (int ni = 0; ni < 2; ++ni) {
                    acc[mi][ni] = __builtin_amdgcn_mfma_f32_16x16x32_f16(ah[mi], bh[ni], acc[mi][ni], 0, 0, 0);
                    acc[mi][ni] = __builtin_amdgcn_mfma_f32_16x16x32_f16(ah[mi], bl[ni], acc[mi][ni], 0, 0, 0);
                    acc[mi][ni] = __builtin_amdgcn_mfma_f32_16x16x32_f16(al[mi], bh[ni], acc[mi][ni], 0, 0, 0);
                }
        }
        __syncthreads();   // drains next-phase glds; all waves done reading cur
    }
#undef STG4

    // epilogue: C/D layout col=lane&15, row=(lane>>4)*4+j (m89-verified)
    float* __restrict__ dst = pbuf + (size_t)z * SLICE;
#pragma unroll
    for (int mi = 0; mi < 2; ++mi) {
        const int row = row0 + (wr << 5) + (mi << 4) + (lq << 2);
#pragma unroll
        for (int ni = 0; ni < 2; ++ni) {
            const int col = col0 + (wc << 5) + (ni << 4) + lr;   // always < 4096
#pragma unroll
            for (int j = 0; j < 4; ++j)
                dst[(size_t)(row + j) * NPROJ + col] = acc[mi][ni][j];
        }
    }
}

// ---------------------------------------------------------------------------
// Tail: cols 4096..4111 (o_g, cancellation-insensitive). 128 blocks x 256 thr;
// 4 threads per output (K split 4x512), fp32 4-way-ILP chunks -> fp64,
// shfl-reduced. Writes pbuf slice0 = val*4096 (exact 2^12, undone by PSCALE),
// slice1 = 0, NO bias (update's psum adds it).
// ---------------------------------------------------------------------------
__global__ __launch_bounds__(256)
void proj_tail4(const float* __restrict__ X0, const float* __restrict__ X1,
                const float* __restrict__ W0, const float* __restrict__ W1,
                float* __restrict__ pbuf)
{
    const int t = threadIdx.x;
    const int o = (blockIdx.x << 6) + (t >> 2);   // 0..8191
    const int q = t & 3;
    const int row = o >> 4;                       // 0..511
    const int col = 4096 + (o & 15);
    const float* __restrict__ X = (q >> 1) ? X1 : X0;
    const float* __restrict__ W = (q >> 1) ? W1 : W0;
    const int kb = (q & 1) << 9;                  // 0 or 512
    const float* __restrict__ xr = X + (size_t)row * 1024 + kb;
    const float* __restrict__ wc = W + (size_t)kb * NPROJ + col;
    float s0 = 0.f, s1 = 0.f, s2 = 0.f, s3 = 0.f;
#pragma unroll 8
    for (int k = 0; k < 512; k += 4) {
        const float4 xv = *(const float4*)(xr + k);
        s0 = fmaf(xv.x, wc[(size_t)(k + 0) * NPROJ], s0);
        s1 = fmaf(xv.y, wc[(size_t)(k + 1) * NPROJ], s1);
        s2 = fmaf(xv.z, wc[(size_t)(k + 2) * NPROJ], s2);
        s3 = fmaf(xv.w, wc[(size_t)(k + 3) * NPROJ], s3);
    }
    double r = (double)((s0 + s1) + (s2 + s3));
    r += __shfl_xor(r, 1, 64);
    r += __shfl_xor(r, 2, 64);
    if (q == 0) {
        pbuf[(size_t)row * NPROJ + col] = (float)(r * 4096.0);
        pbuf[SLICE + (size_t)row * NPROJ + col] = 0.0f;
    }
}

// ---------------------------------------------------------------------------
// Fused mLSTM update, templated over #split-K slices. pscale undoes ASCALE^2.
// ---------------------------------------------------------------------------
template<int NS>
__device__ __forceinline__ double psumN(const float* __restrict__ pb, size_t off,
                                        double pscale, float bv)
{
    double s = 0.0;
#pragma unroll
    for (int i = 0; i < NS; ++i) s += (double)pb[off + (size_t)i * SLICE];
    return s * pscale + (double)bv;
}

template<int NS>
__global__ __launch_bounds__(256)
void mlstm_update_fused(const float* __restrict__ pbuf, const float* __restrict__ bias,
                        const float* __restrict__ C_tm1, const float* __restrict__ n_tm1,
                        float* __restrict__ out, double pscale)
{
    const int bh = blockIdx.x;
    const int b  = bh >> 3;
    const int h  = bh & 7;
    const int t  = threadIdx.x;
    const size_t pb = (size_t)b * NPROJ;

    __shared__ double q_s[128];
    __shared__ double coef_s[128];
    __shared__ double prod_s[128];
    __shared__ double red_s[8][128];
    __shared__ double denom_s;

    const double ig = exp(psumN<NS>(pbuf, pb + 3072 + h, pscale, bias[3072 + h]));
    const double fg = 1.0 / (1.0 + exp(-psumN<NS>(pbuf, pb + 3080 + h, pscale, bias[3080 + h])));

    if (t < 128) {
        const double qv = psumN<NS>(pbuf, pb + h * 128 + t, pscale, bias[h * 128 + t]);
        const double kv = psumN<NS>(pbuf, pb + 1024 + h * 128 + t, pscale, bias[1024 + h * 128 + t]);
        q_s[t] = qv;
        const double cf = ig * kv;
        coef_s[t] = cf;
        const double nv = fma(fg, (double)n_tm1[(size_t)b * 1024 + h * 128 + t], cf);
        out[NOFF + (size_t)b * 1024 + h * 128 + t] = (float)nv;
        prod_s[t] = nv * qv;
    }
    __syncthreads();

    const int g = t >> 5;
    const int s = t & 31;
    const float4* __restrict__ Cin  = (const float4*)(C_tm1 + (size_t)bh * 16384);
    float4*       __restrict__ Cout = (float4*)(out + COFF + (size_t)bh * 16384);
    double v0, v1, v2, v3;
    {
        const size_t vo = pb + 2048 + h * 128 + (s << 2);
        const int    vb = 2048 + h * 128 + (s << 2);
        v0 = psumN<NS>(pbuf, vo + 0, pscale, bias[vb + 0]);
        v1 = psumN<NS>(pbuf, vo + 1, pscale, bias[vb + 1]);
        v2 = psumN<NS>(pbuf, vo + 2, pscale, bias[vb + 2]);
        v3 = psumN<NS>(pbuf, vo + 3, pscale, bias[vb + 3]);
    }

    double r0 = 0.0, r1 = 0.0, r2 = 0.0, r3 = 0.0;
#pragma unroll 4
    for (int it = 0; it < 16; ++it) {
        const int kr = (it << 3) + g;
        const float4 cc = Cin[(kr << 5) + s];
        const double cf = coef_s[kr];
        const double qv = q_s[kr];
        const double c0 = fma(fg, (double)cc.x, cf * v0);
        const double c1 = fma(fg, (double)cc.y, cf * v1);
        const double c2 = fma(fg, (double)cc.z, cf * v2);
        const double c3 = fma(fg, (double)cc.w, cf * v3);
        float4 cn;
        cn.x = (float)c0; cn.y = (float)c1; cn.z = (float)c2; cn.w = (float)c3;
        Cout[(kr << 5) + s] = cn;
        r0 = fma(c0, qv, r0);
        r1 = fma(c1, qv, r1);
        r2 = fma(c2, qv, r2);
        r3 = fma(c3, qv, r3);
    }
    red_s[g][(s << 2) + 0] = r0;
    red_s[g][(s << 2) + 1] = r1;
    red_s[g][(s << 2) + 2] = r2;
    red_s[g][(s << 2) + 3] = r3;
    __syncthreads();

    if (t < 64) {
        double x = prod_s[t] + prod_s[t + 64];
#pragma unroll
        for (int off = 32; off > 0; off >>= 1) x += __shfl_xor(x, off, 64);
        if (t == 0) denom_s = x + 1e-8;
    }
    __syncthreads();

    if (t < 32) {
        double r[4] = {0.0, 0.0, 0.0, 0.0};
#pragma unroll
        for (int gg = 0; gg < 8; ++gg) {
#pragma unroll
            for (int j = 0; j < 4; ++j) r[j] += red_s[gg][(t << 2) + j];
        }
        const double inv = 1.0 / denom_s;
        const size_t oo = pb + 3088 + h * 128 + (t << 2);
        const int    ob = 3088 + h * 128 + (t << 2);
        float4 hv;
        hv.x = (float)((1.0 / (1.0 + exp(-psumN<NS>(pbuf, oo + 0, pscale, bias[ob + 0])))) * (r[0] * inv));
        hv.y = (float)((1.0 / (1.0 + exp(-psumN<NS>(pbuf, oo + 1, pscale, bias[ob + 1])))) * (r[1] * inv));
        hv.z = (float)((1.0 / (1.0 + exp(-psumN<NS>(pbuf, oo + 2, pscale, bias[ob + 2])))) * (r[2] * inv));
        hv.w = (float)((1.0 / (1.0 + exp(-psumN<NS>(pbuf, oo + 3, pscale, bias[ob + 3])))) * (r[3] * inv));
        *(float4*)(out + HOFF + (size_t)b * 1024 + h * 128 + (t << 2)) = hv;
    }
}

// ---------------------------------------------------------------------------
// Fallback A: split-K=4 fp32 VALU GEMM (R10-proven: 246us total, absmax 32).
// ---------------------------------------------------------------------------
__global__ __launch_bounds__(256)
void proj_gemm_sk(const float* __restrict__ X0, const float* __restrict__ X1,
                  const float* __restrict__ W0, const float* __restrict__ W1,
                  float* __restrict__ pbuf)
{
    const int K = 1024;
    const int N = NPROJ;
    __shared__ float As[32][68];
    __shared__ float Bs[32][68];

    const int tid  = threadIdx.x;
    const int row0 = blockIdx.y * 64;
    const int col0 = blockIdx.x * 64;
    const int z    = blockIdx.z;
    const float* __restrict__ A = (z < 2) ? X0 : X1;
    const float* __restrict__ W = (z < 2) ? W0 : W1;
    const int kbase = (z & 1) << 9;
    const int tx = tid & 15, ty = tid >> 4;

    const int ar = tid >> 2;
    const int aq = (tid & 3) << 2;
    const int bk = tid >> 4;
    const int bn = (tid & 15) << 2;
    const int gn = (col0 + bn < N) ? (col0 + bn) : (N - 4);
    const float* __restrict__ arow = A + (size_t)(row0 + ar) * K;

    float  acc32[4][4];
    double acc64[4][4];
#pragma unroll
    for (int i = 0; i < 4; ++i)
#pragma unroll
        for (int j = 0; j < 4; ++j) { acc32[i][j] = 0.f; acc64[i][j] = 0.0; }

    float4 pa0 = *(const float4*)(arow + kbase + aq);
    float4 pa1 = *(const float4*)(arow + kbase + aq + 16);
    float4 pb0 = *(const float4*)(W + (size_t)(kbase + bk) * N + gn);
    float4 pb1 = *(const float4*)(W + (size_t)(kbase + bk + 16) * N + gn);

    for (int kt = 0; kt < 16; ++kt) {
        As[aq + 0][ar] = pa0.x; As[aq + 1][ar] = pa0.y;
        As[aq + 2][ar] = pa0.z; As[aq + 3][ar] = pa0.w;
        As[aq + 16][ar] = pa1.x; As[aq + 17][ar] = pa1.y;
        As[aq + 18][ar] = pa1.z; As[aq + 19][ar] = pa1.w;
        *(float4*)&Bs[bk][bn]      = pb0;
        *(float4*)&Bs[bk + 16][bn] = pb1;
        __syncthreads();

        if (kt + 1 < 16) {
            const int k0n = kbase + ((kt + 1) << 5);
            pa0 = *(const float4*)(arow + k0n + aq);
            pa1 = *(const float4*)(arow + k0n + aq + 16);
            pb0 = *(const float4*)(W + (size_t)(k0n + bk) * N + gn);
            pb1 = *(const float4*)(W + (size_t)(k0n + bk + 16) * N + gn);
        }

#pragma unroll
        for (int kk = 0; kk < 32; ++kk) {
            const float4 av = *(const float4*)&As[kk][ty << 2];
            const float4 bv = *(const float4*)&Bs[kk][tx << 2];
            const float aa[4] = {av.x, av.y, av.z, av.w};
            const float bb[4] = {bv.x, bv.y, bv.z, bv.w};
#pragma unroll
            for (int i = 0; i < 4; ++i)
#pragma unroll
                for (int j = 0; j < 4; ++j)
                    acc32[i][j] = fmaf(aa[i], bb[j], acc32[i][j]);
        }
#pragma unroll
        for (int i = 0; i < 4; ++i)
#pragma unroll
            for (int j = 0; j < 4; ++j) {
                acc64[i][j] += (double)acc32[i][j];
                acc32[i][j] = 0.f;
            }
        __syncthreads();
    }

    float* __restrict__ dst = pbuf + (size_t)z * SLICE;
    const int c = col0 + (tx << 2);
    if (c < N) {
#pragma unroll
        for (int i = 0; i < 4; ++i) {
            const int row = row0 + (ty << 2) + i;
            float4 w;
            w.x = (float)acc64[i][0];
            w.y = (float)acc64[i][1];
            w.z = (float)acc64[i][2];
            w.w = (float)acc64[i][3];
            *(float4*)(dst + (size_t)row * N + c) = w;
        }
    }
}

// ---------------------------------------------------------------------------
// Fallback B: single fp32 GEMM + bias (R3-proven) for tiny ws.
// ---------------------------------------------------------------------------
__global__ __launch_bounds__(256)
void proj_gemm_fp32(const float* __restrict__ X0, const float* __restrict__ X1,
                    const float* __restrict__ W0, const float* __restrict__ W1,
                    const float* __restrict__ bias, float* __restrict__ proj)
{
    const int N = NPROJ;
    const int K = 1024;
    __shared__ float As[16][68];
    __shared__ float Bs[16][68];
    const int tid  = threadIdx.x;
    const int row0 = blockIdx.y * 64;
    const int col0 = blockIdx.x * 64;
    const int tx   = tid & 15;
    const int ty   = tid >> 4;
    float  acc32[4][4];
    double acc64[4][4];
#pragma unroll
    for (int i = 0; i < 4; ++i)
#pragma unroll
        for (int j = 0; j < 4; ++j) { acc32[i][j] = 0.f; acc64[i][j] = 0.0; }
    for (int src = 0; src < 2; ++src) {
        const float* __restrict__ A = src ? X1 : X0;
        const float* __restrict__ W = src ? W1 : W0;
        for (int kt = 0; kt < 64; ++kt) {
            const int k0 = kt << 4;
            {
                const int r  = tid >> 2;
                const int kq = (tid & 3) << 2;
                const float4 a = *(const float4*)(A + (size_t)(row0 + r) * K + k0 + kq);
                As[kq + 0][r] = a.x; As[kq + 1][r] = a.y;
                As[kq + 2][r] = a.z; As[kq + 3][r] = a.w;
            }
            {
                const int kr = tid >> 4;
                const int nc = (tid & 15) << 2;
                const int gn = col0 + nc;
                float4 bv = make_float4(0.f, 0.f, 0.f, 0.f);
                if (gn < N) bv = *(const float4*)(W + (size_t)(k0 + kr) * N + gn);
                *(float4*)&Bs[kr][nc] = bv;
            }
            __syncthreads();
#pragma unroll
            for (int kk = 0; kk < 16; ++kk) {
                const float4 av = *(const float4*)&As[kk][ty << 2];
                const float4 bv = *(const float4*)&Bs[kk][tx << 2];
                const float aa[4] = {av.x, av.y, av.z, av.w};
                const float bb[4] = {bv.x, bv.y, bv.z, bv.w};
#pragma unroll
                for (int i = 0; i < 4; ++i)
#pragma unroll
                    for (int j = 0; j < 4; ++j)
                        acc32[i][j] = fmaf(aa[i], bb[j], acc32[i][j]);
            }
            __syncthreads();
            if (kt & 1) {
#pragma unroll
                for (int i = 0; i < 4; ++i)
#pragma unroll
                    for (int j = 0; j < 4; ++j) {
                        acc64[i][j] += (double)acc32[i][j];
                        acc32[i][j] = 0.f;
                    }
            }
        }
    }
    const int c = col0 + (tx << 2);
    if (c < N) {
#pragma unroll
        for (int i = 0; i < 4; ++i) {
            const int row = row0 + (ty << 2) + i;
            float4 w;
            w.x = (float)(acc64[i][0] + (double)bias[c + 0]);
            w.y = (float)(acc64[i][1] + (double)bias[c + 1]);
            w.z = (float)(acc64[i][2] + (double)bias[c + 2]);
            w.w = (float)(acc64[i][3] + (double)bias[c + 3]);
            *(float4*)(proj + (size_t)row * N + c) = w;
        }
    }
}

__global__ __launch_bounds__(256)
void mlstm_update(const float* __restrict__ proj, const float* __restrict__ C_tm1,
                  const float* __restrict__ n_tm1, float* __restrict__ out)
{
    const int bh = blockIdx.x;
    const int b  = bh >> 3;
    const int h  = bh & 7;
    const int t  = threadIdx.x;
    const float* __restrict__ pr = proj + (size_t)b * NPROJ;

    __shared__ double q_s[128];
    __shared__ double coef_s[128];
    __shared__ double prod_s[128];
    __shared__ double red_s[8][128];
    __shared__ double denom_s;

    const double ig = exp((double)pr[3072 + h]);
    const double fg = 1.0 / (1.0 + exp(-(double)pr[3080 + h]));

    if (t < 128) {
        const double qv = (double)pr[h * 128 + t];
        const double kv = (double)pr[1024 + h * 128 + t];
        q_s[t] = qv;
        const double cf = ig * kv;
        coef_s[t] = cf;
        const double nv = fma(fg, (double)n_tm1[(size_t)b * 1024 + h * 128 + t], cf);
        out[NOFF + (size_t)b * 1024 + h * 128 + t] = (float)nv;
        prod_s[t] = nv * qv;
    }
    __syncthreads();

    const int g = t >> 5;
    const int s = t & 31;
    const float4* __restrict__ Cin  = (const float4*)(C_tm1 + (size_t)bh * 16384);
    float4*       __restrict__ Cout = (float4*)(out + COFF + (size_t)bh * 16384);
    const float4 vf = *(const float4*)(pr + 2048 + h * 128 + (s << 2));
    const double v0 = (double)vf.x, v1 = (double)vf.y, v2 = (double)vf.z, v3 = (double)vf.w;

    double r0 = 0.0, r1 = 0.0, r2 = 0.0, r3 = 0.0;
#pragma unroll 4
    for (int it = 0; it < 16; ++it) {
        const int kr = (it << 3) + g;
        const float4 cc = Cin[(kr << 5) + s];
        const double cf = coef_s[kr];
        const double qv = q_s[kr];
        const double c0 = fma(fg, (double)cc.x, cf * v0);
        const double c1 = fma(fg, (double)cc.y, cf * v1);
        const double c2 = fma(fg, (double)cc.z, cf * v2);
        const double c3 = fma(fg, (double)cc.w, cf * v3);
        float4 cn;
        cn.x = (float)c0; cn.y = (float)c1; cn.z = (float)c2; cn.w = (float)c3;
        Cout[(kr << 5) + s] = cn;
        r0 = fma(c0, qv, r0);
        r1 = fma(c1, qv, r1);
        r2 = fma(c2, qv, r2);
        r3 = fma(c3, qv, r3);
    }
    red_s[g][(s << 2) + 0] = r0;
    red_s[g][(s << 2) + 1] = r1;
    red_s[g][(s << 2) + 2] = r2;
    red_s[g][(s << 2) + 3] = r3;
    __syncthreads();

    if (t < 64) {
        double x = prod_s[t] + prod_s[t + 64];
#pragma unroll
        for (int off = 32; off > 0; off >>= 1) x += __shfl_xor(x, off, 64);
        if (t == 0) denom_s = x + 1e-8;
    }
    __syncthreads();

    if (t < 32) {
        double r[4] = {0.0, 0.0, 0.0, 0.0};
#pragma unroll
        for (int gg = 0; gg < 8; ++gg) {
#pragma unroll
            for (int j = 0; j < 4; ++j) r[j] += red_s[gg][(t << 2) + j];
        }
        const double inv = 1.0 / denom_s;
        const float* oo = pr + 3088 + h * 128 + (t << 2);
        float4 hv;
        hv.x = (float)((1.0 / (1.0 + exp(-(double)oo[0]))) * (r[0] * inv));
        hv.y = (float)((1.0 / (1.0 + exp(-(double)oo[1]))) * (r[1] * inv));
        hv.z = (float)((1.0 / (1.0 + exp(-(double)oo[2]))) * (r[2] * inv));
        hv.w = (float)((1.0 / (1.0 + exp(-(double)oo[3]))) * (r[3] * inv));
        *(float4*)(out + HOFF + (size_t)b * 1024 + h * 128 + (t << 2)) = hv;
    }
}

// ---------------------------------------------------------------------------
extern "C" void kernel_launch(void* const* d_in, const int* in_sizes, int n_in,
                              void* d_out, int out_size, void* d_ws, size_t ws_size,
                              hipStream_t stream)
{
    const float* inputs  = (const float*)d_in[0];   // (512, 1024)
    const float* h_tm1   = (const float*)d_in[1];   // (512, 1024)
    const float* C_tm1   = (const float*)d_in[2];   // (512, 8*128*128)
    const float* n_tm1   = (const float*)d_in[3];   // (512, 8*128)
    const float* kernelW = (const float*)d_in[4];   // (1024, 4112)
    const float* rkernel = (const float*)d_in[5];   // (1024, 4112)
    const float* bias    = (const float*)d_in[6];   // (4112,)
    float* out = (float*)d_out;

    // main-path layout
    const size_t SZ_PB2 = (size_t)2 * SLICE * 4;              // 16,842,752
    const size_t SZ_A   = (size_t)512 * 2048 * 2;             //  2,097,152
    const size_t SZ_WT  = (size_t)4096 * 2048 * 2;            // 16,777,216
    const size_t OFF_AH = SZ_PB2;
    const size_t OFF_AL = OFF_AH + SZ_A;
    const size_t OFF_WH = OFF_AL + SZ_A;
    const size_t OFF_WL = OFF_WH + SZ_WT;
    const size_t NEED_MAIN = OFF_WL + SZ_WT;                  // ~54.6 MB
    const size_t NEED_SK   = (size_t)4 * SLICE * 4;           // 33,685,504
    const size_t NEED_MIN  = (size_t)SLICE * 4;               //  8,421,376

    if (ws_size >= NEED_MAIN) {
        float*  pbuf = (float*)d_ws;
        ushort* Ah = (ushort*)((char*)d_ws + OFF_AH);
        ushort* Al = (ushort*)((char*)d_ws + OFF_AL);
        ushort* Wh = (ushort*)((char*)d_ws + OFF_WH);
        ushort* Wl = (ushort*)((char*)d_ws + OFF_WL);
        split_a2<<<dim3(512), dim3(256), 0, stream>>>(inputs, h_tm1, Ah, Al);
        split_w2<<<dim3(32, 64), dim3(256), 0, stream>>>(kernelW, rkernel, Wh, Wl);
        proj_mfma4<<<dim3(64, 8, 2), dim3(256), 0, stream>>>(Ah, Al, Wh, Wl, pbuf);
        proj_tail4<<<dim3(128), dim3(256), 0, stream>>>(inputs, h_tm1, kernelW, rkernel, pbuf);
        mlstm_update_fused<2><<<dim3(4096), dim3(256), 0, stream>>>(pbuf, bias, C_tm1, n_tm1, out, PSCALE);
    } else if (ws_size >= NEED_SK) {
        float* pbuf = (float*)d_ws;
        proj_gemm_sk<<<dim3(65, 8, 4), dim3(256), 0, stream>>>(inputs, h_tm1, kernelW, rkernel, pbuf);
        mlstm_update_fused<4><<<dim3(4096), dim3(256), 0, stream>>>(pbuf, bias, C_tm1, n_tm1, out, 1.0);
    } else if (ws_size >= NEED_MIN) {
        float* proj = (float*)d_ws;
        proj_gemm_fp32<<<dim3(65, 8), dim3(256), 0, stream>>>(inputs, h_tm1, kernelW, rkernel, bias, proj);
        mlstm_update<<<dim3(4096), dim3(256), 0, stream>>>(proj, C_tm1, n_tm1, out);
    }
}

// Round 15
// 179.786 us; speedup vs baseline: 1.1644x; 1.1644x over previous
//
#include <hip/hip_runtime.h>
#include <hip/hip_fp16.h>
#include <math.h>

// Problem constants
#define NPROJ 4112          // P = 2*H*K + H*V + 2*H + UNITS
#define HOFF  0                                  // h_t  : 512*1024
#define COFF  524288                             // C_t  : 512*8*128*128
#define NOFF  67633152                           // n_t  : 512*1024
#define SLICE 2105344                            // 512*4112 (one split-K partial)
#define WTROWS 4160                              // 4112 padded to 65*64

using f16x8 = __attribute__((ext_vector_type(8))) _Float16;
using f32x4 = __attribute__((ext_vector_type(4))) float;

typedef __attribute__((address_space(1))) const ushort gu16;
typedef __attribute__((address_space(3))) ushort lu16;

#define ASCALE 64.0f        // pre-scale: keeps fp16 lo-parts out of denormal range
#define PSCALE (1.0 / 4096.0)   // exact 2^-12 undo in fp64

__device__ __forceinline__ void fp16_split(float x, ushort& h, ushort& l)
{
    const __half h1 = __float2half(x);
    h = __half_as_ushort(h1);
    l = __half_as_ushort(__float2half(x - __half2float(h1)));
}

// ---------------------------------------------------------------------------
// S1: A = [X0 | X1] * 64  ->  fp16 hi/lo, row-major [512][2048] (k-contig).
// ---------------------------------------------------------------------------
__global__ __launch_bounds__(256)
void split_a2(const float* __restrict__ X0, const float* __restrict__ X1,
              ushort* __restrict__ Ah, ushort* __restrict__ Al)
{
    const int idx8 = (blockIdx.x * 256 + threadIdx.x) << 3;   // 0..1048568
    const int row = idx8 >> 11, k = idx8 & 2047;
    const float* src = (k < 1024) ? (X0 + (size_t)row * 1024 + k)
                                  : (X1 + (size_t)row * 1024 + (k - 1024));
    const float4 v0 = *(const float4*)src;
    const float4 v1 = *(const float4*)(src + 4);
    const float vv[8] = {v0.x, v0.y, v0.z, v0.w, v1.x, v1.y, v1.z, v1.w};
    ushort hh[8], ll[8];
#pragma unroll
    for (int i = 0; i < 8; ++i) fp16_split(vv[i] * ASCALE, hh[i], ll[i]);
    uint4 uh, ul;
    uh.x = hh[0] | ((unsigned)hh[1] << 16); uh.y = hh[2] | ((unsigned)hh[3] << 16);
    uh.z = hh[4] | ((unsigned)hh[5] << 16); uh.w = hh[6] | ((unsigned)hh[7] << 16);
    ul.x = ll[0] | ((unsigned)ll[1] << 16); ul.y = ll[2] | ((unsigned)ll[3] << 16);
    ul.z = ll[4] | ((unsigned)ll[5] << 16); ul.w = ll[6] | ((unsigned)ll[7] << 16);
    *(uint4*)(Ah + idx8) = uh;
    *(uint4*)(Al + idx8) = ul;
}

// ---------------------------------------------------------------------------
// S2: Wt = transpose([W0;W1]) * 64 -> fp16 hi/lo, [4160][2048] (n-major,
// k-contig); rows 4112..4159 zero. LDS-tiled 64x64. Grid (32 k, 65 n).
// ---------------------------------------------------------------------------
__global__ __launch_bounds__(256)
void split_w2(const float* __restrict__ W0, const float* __restrict__ W1,
              ushort* __restrict__ Wh, ushort* __restrict__ Wl)
{
    __shared__ __align__(16) ushort Th[64][72];
    __shared__ __align__(16) ushort Tl[64][72];
    const int t = threadIdx.x;
    const int kcat0 = blockIdx.x * 64;       // 0..1984
    const int n0    = blockIdx.y * 64;       // 0..4096
    const float* __restrict__ W = (kcat0 < 1024) ? W0 : W1;
    const int kbase = kcat0 & 1023;
    const int kr = t >> 4;                   // 0..15
    const int nc = (t & 15) << 2;            // 0..60
    const bool ok = (n0 + nc) < NPROJ;
#pragma unroll
    for (int ii = 0; ii < 4; ++ii) {
        const int kl = kr + ii * 16;
        float4 w = make_float4(0.f, 0.f, 0.f, 0.f);
        if (ok) w = *(const float4*)(W + (size_t)(kbase + kl) * NPROJ + n0 + nc);
        const float x[4] = {w.x, w.y, w.z, w.w};
#pragma unroll
        for (int c = 0; c < 4; ++c) {
            ushort hh, ll;
            fp16_split(x[c] * ASCALE, hh, ll);
            Th[nc + c][kl] = hh;
            Tl[nc + c][kl] = ll;
        }
    }
    __syncthreads();
#pragma unroll
    for (int p = 0; p < 2; ++p) {
        const int c  = t + (p << 8);         // 0..511
        const int nn = c >> 3;
        const int kq = (c & 7) << 3;
        *(uint4*)(Wh + (size_t)(n0 + nn) * 2048 + kcat0 + kq) = *(uint4*)&Th[nn][kq];
        *(uint4*)(Wl + (size_t)(n0 + nn) * 2048 + kcat0 + kq) = *(uint4*)&Tl[nn][kq];
    }
}

// ---------------------------------------------------------------------------
// G: pbuf[z] = Xz * Wz (scaled) via fp16x2 MFMA, 3 terms (hh, hl, lh; ll
// dropped — ~2^-22 rel, proven accuracy-safe in R13/R14 at absmax 64).
// EXACT R12 structure (183.2us session-best): tile 64x64, BK=64, single
// 32KB LDS buffer (5 blocks/CU — TLP hides the stage drain; every
// double-buffer/occupancy-trading variant regressed: R13 +10us, R14 +26us).
// Staging: global_load_lds w16, XOR-8 swizzle (pre-swizzled SOURCE, linear
// dest, swizzled read). Grid (65, 8, 2) = 1040 blocks.
// ---------------------------------------------------------------------------
__global__ __launch_bounds__(256)
void proj_mfma2(const ushort* __restrict__ Ah, const ushort* __restrict__ Al,
                const ushort* __restrict__ Wh, const ushort* __restrict__ Wl,
                float* __restrict__ pbuf)
{
    __shared__ __align__(16) ushort As[2][4096];   // [lvl][r*64 + slot*8]
    __shared__ __align__(16) ushort Bs[2][4096];   // slot = logical_chunk ^ (r&7)

    const int t    = threadIdx.x;
    const int col0 = blockIdx.x * 64;        // 0..4096 (Wt padded/zeroed)
    const int row0 = blockIdx.y * 64;
    const int z    = blockIdx.z;             // kcat base = z*1024
    const int lane = t & 63, wid = t >> 6;
    const int wr = wid >> 1, wc = wid & 1;
    const int lr = lane & 15, lq = lane >> 4;

    // staging: thread covers 16B chunks c0 = t, c1 = t+256
    const int r0s = t >> 3,        ch0 = t & 7;
    const int r1s = r0s + 32;      // (t+256)>>3 ; chunk same (t+256)&7 == ch0
    const int so0 = (ch0 ^ (r0s & 7)) << 3;      // pre-swizzled src offset (halves)
    const int so1 = (ch0 ^ (r1s & 7)) << 3;
    const size_t kb = (size_t)z << 10;
    const size_t arow0 = (size_t)(row0 + r0s) * 2048 + kb;
    const size_t arow1 = (size_t)(row0 + r1s) * 2048 + kb;
    const size_t brow0 = (size_t)(col0 + r0s) * 2048 + kb;
    const size_t brow1 = (size_t)(col0 + r1s) * 2048 + kb;
    const int d0 = t << 3;                   // lds dest (halves): linear c*8
    const int d1 = d0 + 2048;

    // fragment read offsets (halves): logical chunk = kh*4+lq, row-swizzled
    int aoff[2][2], boff[2][2];
#pragma unroll
    for (int mi = 0; mi < 2; ++mi)
#pragma unroll
        for (int kh = 0; kh < 2; ++kh) {
            const int ra = (wr << 5) + (mi << 4) + lr;
            aoff[mi][kh] = ra * 64 + ((((kh << 2) + lq) ^ (ra & 7)) << 3);
            const int rb = (wc << 5) + (mi << 4) + lr;
            boff[mi][kh] = rb * 64 + ((((kh << 2) + lq) ^ (rb & 7)) << 3);
        }

    f32x4 acc[2][2] = {};

    for (int kt = 0; kt < 16; ++kt) {
        const int ko = kt << 6;
        __builtin_amdgcn_global_load_lds((gu16*)(Ah + arow0 + ko + so0), (lu16*)&As[0][d0], 16, 0, 0);
        __builtin_amdgcn_global_load_lds((gu16*)(Ah + arow1 + ko + so1), (lu16*)&As[0][d1], 16, 0, 0);
        __builtin_amdgcn_global_load_lds((gu16*)(Al + arow0 + ko + so0), (lu16*)&As[1][d0], 16, 0, 0);
        __builtin_amdgcn_global_load_lds((gu16*)(Al + arow1 + ko + so1), (lu16*)&As[1][d1], 16, 0, 0);
        __builtin_amdgcn_global_load_lds((gu16*)(Wh + brow0 + ko + so0), (lu16*)&Bs[0][d0], 16, 0, 0);
        __builtin_amdgcn_global_load_lds((gu16*)(Wh + brow1 + ko + so1), (lu16*)&Bs[0][d1], 16, 0, 0);
        __builtin_amdgcn_global_load_lds((gu16*)(Wl + brow0 + ko + so0), (lu16*)&Bs[1][d0], 16, 0, 0);
        __builtin_amdgcn_global_load_lds((gu16*)(Wl + brow1 + ko + so1), (lu16*)&Bs[1][d1], 16, 0, 0);
        __syncthreads();   // drains vmcnt before barrier -> data landed

#pragma unroll
        for (int kh = 0; kh < 2; ++kh) {
            f16x8 ah[2], al[2], bh[2], bl[2];
#pragma unroll
            for (int mi = 0; mi < 2; ++mi) {
                ah[mi] = *(const f16x8*)&As[0][aoff[mi][kh]];
                al[mi] = *(const f16x8*)&As[1][aoff[mi][kh]];
                bh[mi] = *(const f16x8*)&Bs[0][boff[mi][kh]];
                bl[mi] = *(const f16x8*)&Bs[1][boff[mi][kh]];
            }
#pragma unroll
            for (int mi = 0; mi < 2; ++mi)
#pragma unroll
                for (int ni = 0; ni < 2; ++ni) {
                    acc[mi][ni] = __builtin_amdgcn_mfma_f32_16x16x32_f16(ah[mi], bh[ni], acc[mi][ni], 0, 0, 0);
                    acc[mi][ni] = __builtin_amdgcn_mfma_f32_16x16x32_f16(ah[mi], bl[ni], acc[mi][ni], 0, 0, 0);
                    acc[mi][ni] = __builtin_amdgcn_mfma_f32_16x16x32_f16(al[mi], bh[ni], acc[mi][ni], 0, 0, 0);
                }
        }
        __syncthreads();   // all reads done before next tile's glds overwrite
    }

    // epilogue: C/D layout col=lane&15, row=(lane>>4)*4+j (m89-verified)
    float* __restrict__ dst = pbuf + (size_t)z * SLICE;
#pragma unroll
    for (int mi = 0; mi < 2; ++mi) {
        const int row = row0 + (wr << 5) + (mi << 4) + (lq << 2);
#pragma unroll
        for (int ni = 0; ni < 2; ++ni) {
            const int col = col0 + (wc << 5) + (ni << 4) + lr;
            if (col < NPROJ) {
#pragma unroll
                for (int j = 0; j < 4; ++j)
                    dst[(size_t)(row + j) * NPROJ + col] = acc[mi][ni][j];
            }
        }
    }
}

// ---------------------------------------------------------------------------
// Fused mLSTM update, templated over #split-K slices. pscale undoes ASCALE^2.
// ---------------------------------------------------------------------------
template<int NS>
__device__ __forceinline__ double psumN(const float* __restrict__ pb, size_t off,
                                        double pscale, float bv)
{
    double s = 0.0;
#pragma unroll
    for (int i = 0; i < NS; ++i) s += (double)pb[off + (size_t)i * SLICE];
    return s * pscale + (double)bv;
}

template<int NS>
__global__ __launch_bounds__(256)
void mlstm_update_fused(const float* __restrict__ pbuf, const float* __restrict__ bias,
                        const float* __restrict__ C_tm1, const float* __restrict__ n_tm1,
                        float* __restrict__ out, double pscale)
{
    const int bh = blockIdx.x;
    const int b  = bh >> 3;
    const int h  = bh & 7;
    const int t  = threadIdx.x;
    const size_t pb = (size_t)b * NPROJ;

    __shared__ double q_s[128];
    __shared__ double coef_s[128];
    __shared__ double prod_s[128];
    __shared__ double red_s[8][128];
    __shared__ double denom_s;

    const double ig = exp(psumN<NS>(pbuf, pb + 3072 + h, pscale, bias[3072 + h]));
    const double fg = 1.0 / (1.0 + exp(-psumN<NS>(pbuf, pb + 3080 + h, pscale, bias[3080 + h])));

    if (t < 128) {
        const double qv = psumN<NS>(pbuf, pb + h * 128 + t, pscale, bias[h * 128 + t]);
        const double kv = psumN<NS>(pbuf, pb + 1024 + h * 128 + t, pscale, bias[1024 + h * 128 + t]);
        q_s[t] = qv;
        const double cf = ig * kv;
        coef_s[t] = cf;
        const double nv = fma(fg, (double)n_tm1[(size_t)b * 1024 + h * 128 + t], cf);
        out[NOFF + (size_t)b * 1024 + h * 128 + t] = (float)nv;
        prod_s[t] = nv * qv;
    }
    __syncthreads();

    const int g = t >> 5;
    const int s = t & 31;
    const float4* __restrict__ Cin  = (const float4*)(C_tm1 + (size_t)bh * 16384);
    float4*       __restrict__ Cout = (float4*)(out + COFF + (size_t)bh * 16384);
    double v0, v1, v2, v3;
    {
        const size_t vo = pb + 2048 + h * 128 + (s << 2);
        const int    vb = 2048 + h * 128 + (s << 2);
        v0 = psumN<NS>(pbuf, vo + 0, pscale, bias[vb + 0]);
        v1 = psumN<NS>(pbuf, vo + 1, pscale, bias[vb + 1]);
        v2 = psumN<NS>(pbuf, vo + 2, pscale, bias[vb + 2]);
        v3 = psumN<NS>(pbuf, vo + 3, pscale, bias[vb + 3]);
    }

    double r0 = 0.0, r1 = 0.0, r2 = 0.0, r3 = 0.0;
#pragma unroll 4
    for (int it = 0; it < 16; ++it) {
        const int kr = (it << 3) + g;
        const float4 cc = Cin[(kr << 5) + s];
        const double cf = coef_s[kr];
        const double qv = q_s[kr];
        const double c0 = fma(fg, (double)cc.x, cf * v0);
        const double c1 = fma(fg, (double)cc.y, cf * v1);
        const double c2 = fma(fg, (double)cc.z, cf * v2);
        const double c3 = fma(fg, (double)cc.w, cf * v3);
        float4 cn;
        cn.x = (float)c0; cn.y = (float)c1; cn.z = (float)c2; cn.w = (float)c3;
        Cout[(kr << 5) + s] = cn;
        r0 = fma(c0, qv, r0);
        r1 = fma(c1, qv, r1);
        r2 = fma(c2, qv, r2);
        r3 = fma(c3, qv, r3);
    }
    red_s[g][(s << 2) + 0] = r0;
    red_s[g][(s << 2) + 1] = r1;
    red_s[g][(s << 2) + 2] = r2;
    red_s[g][(s << 2) + 3] = r3;
    __syncthreads();

    if (t < 64) {
        double x = prod_s[t] + prod_s[t + 64];
#pragma unroll
        for (int off = 32; off > 0; off >>= 1) x += __shfl_xor(x, off, 64);
        if (t == 0) denom_s = x + 1e-8;
    }
    __syncthreads();

    if (t < 32) {
        double r[4] = {0.0, 0.0, 0.0, 0.0};
#pragma unroll
        for (int gg = 0; gg < 8; ++gg) {
#pragma unroll
            for (int j = 0; j < 4; ++j) r[j] += red_s[gg][(t << 2) + j];
        }
        const double inv = 1.0 / denom_s;
        const size_t oo = pb + 3088 + h * 128 + (t << 2);
        const int    ob = 3088 + h * 128 + (t << 2);
        float4 hv;
        hv.x = (float)((1.0 / (1.0 + exp(-psumN<NS>(pbuf, oo + 0, pscale, bias[ob + 0])))) * (r[0] * inv));
        hv.y = (float)((1.0 / (1.0 + exp(-psumN<NS>(pbuf, oo + 1, pscale, bias[ob + 1])))) * (r[1] * inv));
        hv.z = (float)((1.0 / (1.0 + exp(-psumN<NS>(pbuf, oo + 2, pscale, bias[ob + 2])))) * (r[2] * inv));
        hv.w = (float)((1.0 / (1.0 + exp(-psumN<NS>(pbuf, oo + 3, pscale, bias[ob + 3])))) * (r[3] * inv));
        *(float4*)(out + HOFF + (size_t)b * 1024 + h * 128 + (t << 2)) = hv;
    }
}

// ---------------------------------------------------------------------------
// Fallback A: split-K=4 fp32 VALU GEMM (R10-proven: 246us total, absmax 32).
// ---------------------------------------------------------------------------
__global__ __launch_bounds__(256)
void proj_gemm_sk(const float* __restrict__ X0, const float* __restrict__ X1,
                  const float* __restrict__ W0, const float* __restrict__ W1,
                  float* __restrict__ pbuf)
{
    const int K = 1024;
    const int N = NPROJ;
    __shared__ float As[32][68];
    __shared__ float Bs[32][68];

    const int tid  = threadIdx.x;
    const int row0 = blockIdx.y * 64;
    const int col0 = blockIdx.x * 64;
    const int z    = blockIdx.z;
    const float* __restrict__ A = (z < 2) ? X0 : X1;
    const float* __restrict__ W = (z < 2) ? W0 : W1;
    const int kbase = (z & 1) << 9;
    const int tx = tid & 15, ty = tid >> 4;

    const int ar = tid >> 2;
    const int aq = (tid & 3) << 2;
    const int bk = tid >> 4;
    const int bn = (tid & 15) << 2;
    const int gn = (col0 + bn < N) ? (col0 + bn) : (N - 4);
    const float* __restrict__ arow = A + (size_t)(row0 + ar) * K;

    float  acc32[4][4];
    double acc64[4][4];
#pragma unroll
    for (int i = 0; i < 4; ++i)
#pragma unroll
        for (int j = 0; j < 4; ++j) { acc32[i][j] = 0.f; acc64[i][j] = 0.0; }

    float4 pa0 = *(const float4*)(arow + kbase + aq);
    float4 pa1 = *(const float4*)(arow + kbase + aq + 16);
    float4 pb0 = *(const float4*)(W + (size_t)(kbase + bk) * N + gn);
    float4 pb1 = *(const float4*)(W + (size_t)(kbase + bk + 16) * N + gn);

    for (int kt = 0; kt < 16; ++kt) {
        As[aq + 0][ar] = pa0.x; As[aq + 1][ar] = pa0.y;
        As[aq + 2][ar] = pa0.z; As[aq + 3][ar] = pa0.w;
        As[aq + 16][ar] = pa1.x; As[aq + 17][ar] = pa1.y;
        As[aq + 18][ar] = pa1.z; As[aq + 19][ar] = pa1.w;
        *(float4*)&Bs[bk][bn]      = pb0;
        *(float4*)&Bs[bk + 16][bn] = pb1;
        __syncthreads();

        if (kt + 1 < 16) {
            const int k0n = kbase + ((kt + 1) << 5);
            pa0 = *(const float4*)(arow + k0n + aq);
            pa1 = *(const float4*)(arow + k0n + aq + 16);
            pb0 = *(const float4*)(W + (size_t)(k0n + bk) * N + gn);
            pb1 = *(const float4*)(W + (size_t)(k0n + bk + 16) * N + gn);
        }

#pragma unroll
        for (int kk = 0; kk < 32; ++kk) {
            const float4 av = *(const float4*)&As[kk][ty << 2];
            const float4 bv = *(const float4*)&Bs[kk][tx << 2];
            const float aa[4] = {av.x, av.y, av.z, av.w};
            const float bb[4] = {bv.x, bv.y, bv.z, bv.w};
#pragma unroll
            for (int i = 0; i < 4; ++i)
#pragma unroll
                for (int j = 0; j < 4; ++j)
                    acc32[i][j] = fmaf(aa[i], bb[j], acc32[i][j]);
        }
#pragma unroll
        for (int i = 0; i < 4; ++i)
#pragma unroll
            for (int j = 0; j < 4; ++j) {
                acc64[i][j] += (double)acc32[i][j];
                acc32[i][j] = 0.f;
            }
        __syncthreads();
    }

    float* __restrict__ dst = pbuf + (size_t)z * SLICE;
    const int c = col0 + (tx << 2);
    if (c < N) {
#pragma unroll
        for (int i = 0; i < 4; ++i) {
            const int row = row0 + (ty << 2) + i;
            float4 w;
            w.x = (float)acc64[i][0];
            w.y = (float)acc64[i][1];
            w.z = (float)acc64[i][2];
            w.w = (float)acc64[i][3];
            *(float4*)(dst + (size_t)row * N + c) = w;
        }
    }
}

// ---------------------------------------------------------------------------
// Fallback B: single fp32 GEMM + bias (R3-proven) for tiny ws.
// ---------------------------------------------------------------------------
__global__ __launch_bounds__(256)
void proj_gemm_fp32(const float* __restrict__ X0, const float* __restrict__ X1,
                    const float* __restrict__ W0, const float* __restrict__ W1,
                    const float* __restrict__ bias, float* __restrict__ proj)
{
    const int N = NPROJ;
    const int K = 1024;
    __shared__ float As[16][68];
    __shared__ float Bs[16][68];
    const int tid  = threadIdx.x;
    const int row0 = blockIdx.y * 64;
    const int col0 = blockIdx.x * 64;
    const int tx   = tid & 15;
    const int ty   = tid >> 4;
    float  acc32[4][4];
    double acc64[4][4];
#pragma unroll
    for (int i = 0; i < 4; ++i)
#pragma unroll
        for (int j = 0; j < 4; ++j) { acc32[i][j] = 0.f; acc64[i][j] = 0.0; }
    for (int src = 0; src < 2; ++src) {
        const float* __restrict__ A = src ? X1 : X0;
        const float* __restrict__ W = src ? W1 : W0;
        for (int kt = 0; kt < 64; ++kt) {
            const int k0 = kt << 4;
            {
                const int r  = tid >> 2;
                const int kq = (tid & 3) << 2;
                const float4 a = *(const float4*)(A + (size_t)(row0 + r) * K + k0 + kq);
                As[kq + 0][r] = a.x; As[kq + 1][r] = a.y;
                As[kq + 2][r] = a.z; As[kq + 3][r] = a.w;
            }
            {
                const int kr = tid >> 4;
                const int nc = (tid & 15) << 2;
                const int gn = col0 + nc;
                float4 bv = make_float4(0.f, 0.f, 0.f, 0.f);
                if (gn < N) bv = *(const float4*)(W + (size_t)(k0 + kr) * N + gn);
                *(float4*)&Bs[kr][nc] = bv;
            }
            __syncthreads();
#pragma unroll
            for (int kk = 0; kk < 16; ++kk) {
                const float4 av = *(const float4*)&As[kk][ty << 2];
                const float4 bv = *(const float4*)&Bs[kk][tx << 2];
                const float aa[4] = {av.x, av.y, av.z, av.w};
                const float bb[4] = {bv.x, bv.y, bv.z, bv.w};
#pragma unroll
                for (int i = 0; i < 4; ++i)
#pragma unroll
                    for (int j = 0; j < 4; ++j)
                        acc32[i][j] = fmaf(aa[i], bb[j], acc32[i][j]);
            }
            __syncthreads();
            if (kt & 1) {
#pragma unroll
                for (int i = 0; i < 4; ++i)
#pragma unroll
                    for (int j = 0; j < 4; ++j) {
                        acc64[i][j] += (double)acc32[i][j];
                        acc32[i][j] = 0.f;
                    }
            }
        }
    }
    const int c = col0 + (tx << 2);
    if (c < N) {
#pragma unroll
        for (int i = 0; i < 4; ++i) {
            const int row = row0 + (ty << 2) + i;
            float4 w;
            w.x = (float)(acc64[i][0] + (double)bias[c + 0]);
            w.y = (float)(acc64[i][1] + (double)bias[c + 1]);
            w.z = (float)(acc64[i][2] + (double)bias[c + 2]);
            w.w = (float)(acc64[i][3] + (double)bias[c + 3]);
            *(float4*)(proj + (size_t)row * N + c) = w;
        }
    }
}

__global__ __launch_bounds__(256)
void mlstm_update(const float* __restrict__ proj, const float* __restrict__ C_tm1,
                  const float* __restrict__ n_tm1, float* __restrict__ out)
{
    const int bh = blockIdx.x;
    const int b  = bh >> 3;
    const int h  = bh & 7;
    const int t  = threadIdx.x;
    const float* __restrict__ pr = proj + (size_t)b * NPROJ;

    __shared__ double q_s[128];
    __shared__ double coef_s[128];
    __shared__ double prod_s[128];
    __shared__ double red_s[8][128];
    __shared__ double denom_s;

    const double ig = exp((double)pr[3072 + h]);
    const double fg = 1.0 / (1.0 + exp(-(double)pr[3080 + h]));

    if (t < 128) {
        const double qv = (double)pr[h * 128 + t];
        const double kv = (double)pr[1024 + h * 128 + t];
        q_s[t] = qv;
        const double cf = ig * kv;
        coef_s[t] = cf;
        const double nv = fma(fg, (double)n_tm1[(size_t)b * 1024 + h * 128 + t], cf);
        out[NOFF + (size_t)b * 1024 + h * 128 + t] = (float)nv;
        prod_s[t] = nv * qv;
    }
    __syncthreads();

    const int g = t >> 5;
    const int s = t & 31;
    const float4* __restrict__ Cin  = (const float4*)(C_tm1 + (size_t)bh * 16384);
    float4*       __restrict__ Cout = (float4*)(out + COFF + (size_t)bh * 16384);
    const float4 vf = *(const float4*)(pr + 2048 + h * 128 + (s << 2));
    const double v0 = (double)vf.x, v1 = (double)vf.y, v2 = (double)vf.z, v3 = (double)vf.w;

    double r0 = 0.0, r1 = 0.0, r2 = 0.0, r3 = 0.0;
#pragma unroll 4
    for (int it = 0; it < 16; ++it) {
        const int kr = (it << 3) + g;
        const float4 cc = Cin[(kr << 5) + s];
        const double cf = coef_s[kr];
        const double qv = q_s[kr];
        const double c0 = fma(fg, (double)cc.x, cf * v0);
        const double c1 = fma(fg, (double)cc.y, cf * v1);
        const double c2 = fma(fg, (double)cc.z, cf * v2);
        const double c3 = fma(fg, (double)cc.w, cf * v3);
        float4 cn;
        cn.x = (float)c0; cn.y = (float)c1; cn.z = (float)c2; cn.w = (float)c3;
        Cout[(kr << 5) + s] = cn;
        r0 = fma(c0, qv, r0);
        r1 = fma(c1, qv, r1);
        r2 = fma(c2, qv, r2);
        r3 = fma(c3, qv, r3);
    }
    red_s[g][(s << 2) + 0] = r0;
    red_s[g][(s << 2) + 1] = r1;
    red_s[g][(s << 2) + 2] = r2;
    red_s[g][(s << 2) + 3] = r3;
    __syncthreads();

    if (t < 64) {
        double x = prod_s[t] + prod_s[t + 64];
#pragma unroll
        for (int off = 32; off > 0; off >>= 1) x += __shfl_xor(x, off, 64);
        if (t == 0) denom_s = x + 1e-8;
    }
    __syncthreads();

    if (t < 32) {
        double r[4] = {0.0, 0.0, 0.0, 0.0};
#pragma unroll
        for (int gg = 0; gg < 8; ++gg) {
#pragma unroll
            for (int j = 0; j < 4; ++j) r[j] += red_s[gg][(t << 2) + j];
        }
        const double inv = 1.0 / denom_s;
        const float* oo = pr + 3088 + h * 128 + (t << 2);
        float4 hv;
        hv.x = (float)((1.0 / (1.0 + exp(-(double)oo[0]))) * (r[0] * inv));
        hv.y = (float)((1.0 / (1.0 + exp(-(double)oo[1]))) * (r[1] * inv));
        hv.z = (float)((1.0 / (1.0 + exp(-(double)oo[2]))) * (r[2] * inv));
        hv.w = (float)((1.0 / (1.0 + exp(-(double)oo[3]))) * (r[3] * inv));
        *(float4*)(out + HOFF + (size_t)b * 1024 + h * 128 + (t << 2)) = hv;
    }
}

// ---------------------------------------------------------------------------
extern "C" void kernel_launch(void* const* d_in, const int* in_sizes, int n_in,
                              void* d_out, int out_size, void* d_ws, size_t ws_size,
                              hipStream_t stream)
{
    const float* inputs  = (const float*)d_in[0];   // (512, 1024)
    const float* h_tm1   = (const float*)d_in[1];   // (512, 1024)
    const float* C_tm1   = (const float*)d_in[2];   // (512, 8*128*128)
    const float* n_tm1   = (const float*)d_in[3];   // (512, 8*128)
    const float* kernelW = (const float*)d_in[4];   // (1024, 4112)
    const float* rkernel = (const float*)d_in[5];   // (1024, 4112)
    const float* bias    = (const float*)d_in[6];   // (4112,)
    float* out = (float*)d_out;

    // main-path layout
    const size_t SZ_PB2 = (size_t)2 * SLICE * 4;              // 16,842,752
    const size_t SZ_A   = (size_t)512 * 2048 * 2;             //  2,097,152
    const size_t SZ_WT  = (size_t)WTROWS * 2048 * 2;          // 17,039,360
    const size_t OFF_AH = SZ_PB2;
    const size_t OFF_AL = OFF_AH + SZ_A;
    const size_t OFF_WH = OFF_AL + SZ_A;
    const size_t OFF_WL = OFF_WH + SZ_WT;
    const size_t NEED_MAIN = OFF_WL + SZ_WT;                  // 55,115,776
    const size_t NEED_SK   = (size_t)4 * SLICE * 4;           // 33,685,504
    const size_t NEED_MIN  = (size_t)SLICE * 4;               //  8,421,376

    if (ws_size >= NEED_MAIN) {
        float*  pbuf = (float*)d_ws;
        ushort* Ah = (ushort*)((char*)d_ws + OFF_AH);
        ushort* Al = (ushort*)((char*)d_ws + OFF_AL);
        ushort* Wh = (ushort*)((char*)d_ws + OFF_WH);
        ushort* Wl = (ushort*)((char*)d_ws + OFF_WL);
        split_a2<<<dim3(512), dim3(256), 0, stream>>>(inputs, h_tm1, Ah, Al);
        split_w2<<<dim3(32, 65), dim3(256), 0, stream>>>(kernelW, rkernel, Wh, Wl);
        proj_mfma2<<<dim3(65, 8, 2), dim3(256), 0, stream>>>(Ah, Al, Wh, Wl, pbuf);
        mlstm_update_fused<2><<<dim3(4096), dim3(256), 0, stream>>>(pbuf, bias, C_tm1, n_tm1, out, PSCALE);
    } else if (ws_size >= NEED_SK) {
        float* pbuf = (float*)d_ws;
        proj_gemm_sk<<<dim3(65, 8, 4), dim3(256), 0, stream>>>(inputs, h_tm1, kernelW, rkernel, pbuf);
        mlstm_update_fused<4><<<dim3(4096), dim3(256), 0, stream>>>(pbuf, bias, C_tm1, n_tm1, out, 1.0);
    } else if (ws_size >= NEED_MIN) {
        float* proj = (float*)d_ws;
        proj_gemm_fp32<<<dim3(65, 8), dim3(256), 0, stream>>>(inputs, h_tm1, kernelW, rkernel, bias, proj);
        mlstm_update<<<dim3(4096), dim3(256), 0, stream>>>(proj, C_tm1, n_tm1, out);
    }
}